// Round 9
// baseline (369.744 us; speedup 1.0000x reference)
//
#include <hip/hip_runtime.h>

// ---------------- problem constants ----------------
static const int N_NODES = 20000;
static const int N_EDGES = 320000;
static const int GDIM    = 256;   // input feature dim
static const int H1DIM   = 256;   // RGCN output dim
static const int C2DIM   = 512;   // HEADS * H2
static const int NREL    = 8;
static const int NSEG    = N_NODES * NREL;   // 160000

typedef _Float16 __attribute__((ext_vector_type(8))) half8;
typedef _Float16 __attribute__((ext_vector_type(4))) half4;
typedef _Float16 __attribute__((ext_vector_type(2))) half2v;
typedef __attribute__((ext_vector_type(4))) float f32x4;

__device__ __forceinline__ void gload_lds16(const void* g, void* l) {
  __builtin_amdgcn_global_load_lds(
      (const __attribute__((address_space(1))) unsigned int*)g,
      (__attribute__((address_space(3))) unsigned int*)l, 16, 0, 0);
}

// bijective XCD-chunked block swizzle (m204): contiguous wgid range per XCD,
// decoded bx-fastest -> same-A-panel tiles land on one XCD's L2.
__device__ __forceinline__ void swz_bxy(int& bx, int& by) {
  int nx   = gridDim.x;
  int nwg  = nx * gridDim.y;
  int orig = blockIdx.y * nx + blockIdx.x;
  int xcd  = orig & 7;
  int q    = nwg >> 3, r = nwg & 7;
  int base = xcd < r ? xcd * (q + 1) : r * (q + 1) + (xcd - r) * q;
  int wgid = base + (orig >> 3);
  bx = wgid % nx; by = wgid / nx;
}

// ---------------- fp16 MFMA GEMM: C = A(MxK) @ Bt(NxK)^T + bias ----------------
// 128x128 tile, 4 waves (2x2), BK=64. global_load_lds dwordx4 staging with
// linear LDS dest + pre-swizzled global source (rule-21 involution c ^= row&7).
template<int OUT_HALF>
__global__ __launch_bounds__(256) void gemm_mfma_k(
    const _Float16* __restrict__ A, const _Float16* __restrict__ Bt,
    const float* __restrict__ bias, void* __restrict__ Cout,
    int M, int N, int K)
{
  __shared__ _Float16 As[128 * 64];
  __shared__ _Float16 Bs[128 * 64];
  int bx, by; swz_bxy(bx, by);
  const int tid  = threadIdx.x;
  const int wid  = tid >> 6, lane = tid & 63;
  const int wr   = wid >> 1, wc = wid & 1;
  const int brow = by * 128;
  const int bcol = bx * 128;
  const int l15  = lane & 15, lhi = lane >> 4;
  const int srow = wid * 32;
  const int lrow = lane >> 3;
  const int lchk = lane & 7;

  f32x4 acc[4][4] = {};

  for (int k0 = 0; k0 < K; k0 += 64) {
    __syncthreads();
#pragma unroll
    for (int i = 0; i < 4; ++i) {
      int row = srow + i * 8 + lrow;
      int gc  = lchk ^ (row & 7);
      gload_lds16(A  + (size_t)(brow + row) * K + k0 + gc * 8,
                  &As[(srow + i * 8) * 64]);
      gload_lds16(Bt + (size_t)(bcol + row) * K + k0 + gc * 8,
                  &Bs[(srow + i * 8) * 64]);
    }
    __syncthreads();
#pragma unroll
    for (int kf = 0; kf < 2; ++kf) {
      int cc = kf * 4 + lhi;
      half8 af[4], bfr[4];
#pragma unroll
      for (int mi = 0; mi < 4; ++mi) {
        int row = wr * 64 + mi * 16 + l15;
        af[mi] = ((const half8*)As)[row * 8 + (cc ^ (row & 7))];
      }
#pragma unroll
      for (int ni = 0; ni < 4; ++ni) {
        int row = wc * 64 + ni * 16 + l15;
        bfr[ni] = ((const half8*)Bs)[row * 8 + (cc ^ (row & 7))];
      }
#pragma unroll
      for (int mi = 0; mi < 4; ++mi)
#pragma unroll
        for (int ni = 0; ni < 4; ++ni)
          acc[mi][ni] = __builtin_amdgcn_mfma_f32_16x16x32_f16(
              af[mi], bfr[ni], acc[mi][ni], 0, 0, 0);
    }
  }
#pragma unroll
  for (int ni = 0; ni < 4; ++ni) {
    int col = bcol + wc * 64 + ni * 16 + l15;
    float bb = bias ? bias[col] : 0.f;
#pragma unroll
    for (int mi = 0; mi < 4; ++mi) {
      int row0 = brow + wr * 64 + mi * 16 + lhi * 4;
#pragma unroll
      for (int j = 0; j < 4; ++j) {
        int r = row0 + j;
        if (r >= M) continue;
        float val = acc[mi][ni][j] + bb;
        if (OUT_HALF) ((_Float16*)Cout)[(size_t)r * N + col] = (_Float16)val;
        else          ((float*)Cout)[(size_t)r * N + col] = val;
      }
    }
  }
}

// ---------------- fused prep: hist + W conversions + x->fp16 ----------------
// blocks [0,1250): hist; [1250,3554): Wt_cat2; [3554,5602): Wt_qk+bias; [5602,10602): xh
// Wt_cat2 (2304 rows n2, 256 cols k): n2<256 -> W_root[:,n2]; else rel slice.
__global__ __launch_bounds__(256) void prep_k(
    const int* __restrict__ dst, const int* __restrict__ et, int* __restrict__ hist,
    const float* __restrict__ W_root, const float* __restrict__ W_rel,
    _Float16* __restrict__ Wt_cat2,
    const float* __restrict__ Wq, const float* __restrict__ Wk,
    const float* __restrict__ Wv, const float* __restrict__ Ws,
    const float* __restrict__ bq, const float* __restrict__ bk,
    const float* __restrict__ bv, const float* __restrict__ bs,
    _Float16* __restrict__ Wt_qk, float* __restrict__ bias_cat,
    const float* __restrict__ x, _Float16* __restrict__ xh)
{
  int b = blockIdx.x, tid = threadIdx.x;
  if (b < 1250) {                               // edge histogram
    int e = b * 256 + tid;
    if (e < N_EDGES) atomicAdd(&hist[dst[e] * NREL + et[e]], 1);
  } else if (b < 3554) {                        // Wt_cat2: 2304 x 256
    int idx = (b - 1250) * 256 + tid;           // < 589,824
    int n2 = idx >> 8, k = idx & 255;
    float v;
    if (n2 < 256) v = W_root[(size_t)k * H1DIM + n2];
    else {
      int rr = (n2 - 256) >> 8, c = (n2 - 256) & 255;
      v = W_rel[((size_t)rr * 256 + k) * 256 + c];
    }
    Wt_cat2[idx] = (_Float16)v;
  } else if (b < 5602) {                        // Wt_qk: 2048 x 256 (+ bias)
    int idx = (b - 3554) * 256 + tid;           // < 524,288
    int n = idx >> 8, k = idx & 255;
    int sel = n >> 9, c = n & 511;
    const float* W = sel == 0 ? Wq : sel == 1 ? Wk : sel == 2 ? Wv : Ws;
    Wt_qk[(size_t)n * 256 + k] = (_Float16)W[(size_t)k * C2DIM + c];
    if (k == 0) {
      const float* B = sel == 0 ? bq : sel == 1 ? bk : sel == 2 ? bv : bs;
      bias_cat[n] = B[c];
    }
  } else {                                      // x -> fp16, float4 granularity
    int i = (b - 5602) * 256 + tid;             // < 1,280,000
    float4 v = ((const float4*)x)[i];
    half4 o = {(_Float16)v.x, (_Float16)v.y, (_Float16)v.z, (_Float16)v.w};
    ((half4*)xh)[i] = o;
  }
}

// ---------------- scan: local pass ----------------
__global__ __launch_bounds__(1024) void scan_local_k(
    const int* __restrict__ in, int* __restrict__ out, int* __restrict__ bsum, int n)
{
  __shared__ int s[1024];
  int gi = blockIdx.x * 1024 + threadIdx.x;
  int v = gi < n ? in[gi] : 0;
  s[threadIdx.x] = v; __syncthreads();
  for (int off = 1; off < 1024; off <<= 1) {
    int t = threadIdx.x >= off ? s[threadIdx.x - off] : 0;
    __syncthreads();
    s[threadIdx.x] += t;
    __syncthreads();
  }
  if (gi < n) out[gi] = s[threadIdx.x] - v;
  if (threadIdx.x == 1023) bsum[blockIdx.x] = s[1023];
}

// addoff: each block re-scans bsum itself (nb<=1024), then offsets + cursor init
__global__ __launch_bounds__(1024) void scan_addoff_k(
    int* __restrict__ off, const int* __restrict__ bsum,
    int* __restrict__ cur, int n, int nb)
{
  __shared__ int s[1024];
  int t = threadIdx.x;
  int v = t < nb ? bsum[t] : 0;
  s[t] = v; __syncthreads();
  for (int o = 1; o < 1024; o <<= 1) {
    int u = t >= o ? s[t - o] : 0;
    __syncthreads();
    s[t] += u;
    __syncthreads();
  }
  int blockOff = blockIdx.x == 0 ? 0 : s[blockIdx.x - 1];
  int gi = blockIdx.x * 1024 + t;
  if (gi < n) {
    int val = off[gi] + blockOff;
    off[gi] = val;
    cur[gi] = val;
  }
  if (gi == 0) off[n] = N_EDGES;
}

__global__ void reorder_k(const int* __restrict__ src, const int* __restrict__ dst,
                          const int* __restrict__ et,
                          int* __restrict__ cur, int* __restrict__ esrc)
{
  int e = blockIdx.x * blockDim.x + threadIdx.x;
  if (e >= N_EDGES) return;
  int seg = dst[e] * NREL + et[e];
  esrc[atomicAdd(&cur[seg], 1)] = src[e];
}

// ---------------- aggregate Y -> h1: h1[d] = Y[d,0:256] + b + sum_r mean Y[src,rel slice] ----------------
__global__ __launch_bounds__(256) void agg_h1_k(
    const _Float16* __restrict__ Y, const float* __restrict__ b_rgcn,
    const int* __restrict__ off, const int* __restrict__ esrc,
    _Float16* __restrict__ h1h)
{
  int d = blockIdx.x * 4 + (threadIdx.x >> 6);
  if (d >= N_NODES) return;
  int lane = threadIdx.x & 63;
  half4 rt = ((const half4*)(Y + (size_t)d * 2304))[lane];     // root slice
  float4 bb = ((const float4*)b_rgcn)[lane];
  float4 acc = make_float4((float)rt.x + bb.x, (float)rt.y + bb.y,
                           (float)rt.z + bb.z, (float)rt.w + bb.w);
  for (int r = 0; r < NREL; ++r) {
    int seg = d * NREL + r;
    int beg = off[seg], end = off[seg + 1];
    if (beg >= end) continue;
    float4 a2 = make_float4(0.f, 0.f, 0.f, 0.f);
    for (int e = beg; e < end; ++e) {
      int s = esrc[e];
      half4 v = ((const half4*)(Y + (size_t)s * 2304 + 256 + r * 256))[lane];
      a2.x += (float)v.x; a2.y += (float)v.y;
      a2.z += (float)v.z; a2.w += (float)v.w;
    }
    float inv = 1.0f / (float)(end - beg);
    acc.x += a2.x * inv; acc.y += a2.y * inv;
    acc.z += a2.z * inv; acc.w += a2.w * inv;
  }
  half4 o = {(_Float16)acc.x, (_Float16)acc.y, (_Float16)acc.z, (_Float16)acc.w};
  ((half4*)(h1h + (size_t)d * 256))[lane] = o;
}

// ---------------- fused attention: QKVS row = [q|k|v|skip] fp16; writes fp16 outh ----------------
__global__ __launch_bounds__(256) void attn_fused_k(
    const _Float16* __restrict__ qkvs,
    const int* __restrict__ off, const int* __restrict__ esrc,
    _Float16* __restrict__ outh)
{
  int d = blockIdx.x * 4 + (threadIdx.x >> 6);
  if (d >= N_NODES) return;
  int lane = threadIdx.x & 63;
  half8 qr = ((const half8*)(qkvs + (size_t)d * 2048))[lane];
  float qf[8];
#pragma unroll
  for (int j = 0; j < 8; ++j) qf[j] = (float)qr[j];
  float m = -3.4e38f, ssum = 0.f;
  float av[8] = {};
  int beg = off[d * NREL], end = off[d * NREL + NREL];
  half8 krN = {}, vrN = {};
  if (beg < end) {
    int s0 = esrc[beg];
    const half8* row = (const half8*)(qkvs + (size_t)s0 * 2048 + 512);
    krN = row[lane];
    vrN = row[64 + lane];
  }
  for (int e = beg; e < end; ++e) {
    half8 kr = krN, vr = vrN;
    if (e + 1 < end) {
      int s1 = esrc[e + 1];
      const half8* row = (const half8*)(qkvs + (size_t)s1 * 2048 + 512);
      krN = row[lane];
      vrN = row[64 + lane];
    }
    float p = 0.f;
#pragma unroll
    for (int j = 0; j < 8; ++j) p += qf[j] * (float)kr[j];
    p += __shfl_xor(p, 1); p += __shfl_xor(p, 2);
    p += __shfl_xor(p, 4); p += __shfl_xor(p, 8);
    float a = p * 0.08838834764831845f;      // 1/sqrt(128)
    float mn = fmaxf(m, a);
    float corr = __expf(m - mn), w = __expf(a - mn);
    ssum = ssum * corr + w;
#pragma unroll
    for (int j = 0; j < 8; ++j) av[j] = av[j] * corr + w * (float)vr[j];
    m = mn;
  }
  float inv = 1.0f / fmaxf(ssum, 1e-16f);
  half8 sr = ((const half8*)(qkvs + (size_t)d * 2048 + 1536))[lane];  // skip
  half8 o;
#pragma unroll
  for (int j = 0; j < 8; ++j) o[j] = (_Float16)(av[j] * inv + (float)sr[j]);
  ((half8*)(outh + (size_t)d * C2DIM))[lane] = o;
}

// ---------------- BN on fp16 input ----------------
__global__ __launch_bounds__(256) void bn_stats_k(
    const _Float16* __restrict__ x, float* __restrict__ sums, float* __restrict__ sumsq)
{
  int t = threadIdx.x;            // cols 2t, 2t+1
  float s0 = 0.f, q0 = 0.f, s1 = 0.f, q1 = 0.f;
  for (int row = blockIdx.x; row < N_NODES; row += gridDim.x) {
    half2v v = ((const half2v*)(x + (size_t)row * C2DIM))[t];
    float a = (float)v.x, b = (float)v.y;
    s0 += a; q0 += a * a; s1 += b; q1 += b * b;
  }
  atomicAdd(&sums[2 * t], s0);  atomicAdd(&sums[2 * t + 1], s1);
  atomicAdd(&sumsq[2 * t], q0); atomicAdd(&sumsq[2 * t + 1], q1);
}

// apply: fp16 in, fp32 out, inline scale/shift (statically-indexed, no UB)
__global__ void bn_apply_k(const _Float16* __restrict__ xin, float* __restrict__ xout,
                           const float* __restrict__ sums, const float* __restrict__ sumsq,
                           const float* __restrict__ gamma, const float* __restrict__ beta,
                           int total8)
{
  int i = blockIdx.x * blockDim.x + threadIdx.x;
  if (i >= total8) return;
  int c0 = (i & 63) * 8;
  half8 v = ((const half8*)xin)[i];
  float o[8];
#pragma unroll
  for (int j = 0; j < 8; ++j) {
    int c = c0 + j;
    float mu  = sums[c] * (1.0f / N_NODES);
    float var = sumsq[c] * (1.0f / N_NODES) - mu * mu;
    float sc  = gamma[c] * rsqrtf(var + 1e-5f);
    float val = ((float)v[j] - mu) * sc + beta[c];
    o[j] = val >= 0.f ? val : 0.01f * val;
  }
  ((float4*)xout)[i * 2]     = make_float4(o[0], o[1], o[2], o[3]);
  ((float4*)xout)[i * 2 + 1] = make_float4(o[4], o[5], o[6], o[7]);
}

// ---------------- launch ----------------
extern "C" void kernel_launch(void* const* d_in, const int* in_sizes, int n_in,
                              void* d_out, int out_size, void* d_ws, size_t ws_size,
                              hipStream_t stream)
{
  const float* x      = (const float*)d_in[0];
  const int*   ei     = (const int*)d_in[2];
  const int*   src    = ei;
  const int*   dst    = ei + N_EDGES;
  const int*   etype  = (const int*)d_in[3];
  const float* W_rel  = (const float*)d_in[4];
  const float* W_root = (const float*)d_in[5];
  const float* b_rgcn = (const float*)d_in[6];
  const float* W_q = (const float*)d_in[7];  const float* b_q = (const float*)d_in[8];
  const float* W_k = (const float*)d_in[9];  const float* b_k = (const float*)d_in[10];
  const float* W_v = (const float*)d_in[11]; const float* b_v = (const float*)d_in[12];
  const float* W_s = (const float*)d_in[13]; const float* b_s = (const float*)d_in[14];
  const float* gamma = (const float*)d_in[15];
  const float* beta  = (const float*)d_in[16];
  float* out = (float*)d_out;

  // ---- workspace layout ----
  char* ws = (char*)d_ws;
  _Float16* Y      = (_Float16*)(ws + 0);          // N x 2304 fp16 = 92,160,000
  _Float16* QKVS   = (_Float16*)(ws + 0);          // reuse after agg: N x 2048 = 81,920,000
  _Float16* outh   = (_Float16*)(ws + 81920000);   // N x 512 fp16 = 20,480,000 (clobbers Wt/h1h, dead)
  _Float16* Wt_cat = (_Float16*)(ws + 92160000);   // 2304 x 256 fp16 = 1,179,648
  _Float16* Wt_qk  = (_Float16*)(ws + 93339648);   // 2048 x 256 fp16 = 1,048,576
  _Float16* h1h    = (_Float16*)(ws + 94388224);   // N x 256 fp16 = 10,240,000
  _Float16* xh     = h1h;                          // xh aliases h1h (dead before agg writes h1)

  char* C = ws + 104628224;                    // CSR + small area
  int*   cur      = (int*)(C + 0);             // 640,000  (hist, then cursor)
  float* bns      = (float*)(C + 640000);      // 8,192
  float* bias_cat = (float*)(C + 648192);      // 8,192
  int*   off      = (int*)(C + 656384);        // 640,016
  int*   esrc     = (int*)(C + 1296400);       // 1,280,000
  int*   bsum     = (int*)(C + 2576400);       // 4,096  (ends 107,208,720)
  float* bnsum = bns, *bnsq = bns + 512;

  hipMemsetAsync(C, 0, 648192, stream);        // hist + bns in one call

  dim3 blk(256);
  const int NB = (NSEG + 1023) / 1024;         // 157

  // ---- fused prep: hist + weight conversions + x->fp16 ----
  prep_k<<<dim3(10602), blk, 0, stream>>>(
      dst, etype, cur,
      W_root, W_rel, Wt_cat,
      W_q, W_k, W_v, W_s, b_q, b_k, b_v, b_s, Wt_qk, bias_cat,
      x, xh);

  // ---- CSR scan + reorder ----
  scan_local_k<<<dim3(NB), dim3(1024), 0, stream>>>(cur, off, bsum, NSEG);
  scan_addoff_k<<<dim3(NB), dim3(1024), 0, stream>>>(off, bsum, cur, NSEG, NB);
  reorder_k<<<dim3((N_EDGES + 255) / 256), blk, 0, stream>>>(
      src, dst, etype, cur, esrc);

  // ---- Y = xh @ [W_root | W_rel_all] : M=20000, N=2304, K=256 ----
  gemm_mfma_k<1><<<dim3(2304 / 128, (N_NODES + 127) / 128), blk, 0, stream>>>(
      xh, Wt_cat, nullptr, Y, N_NODES, 2304, 256);

  // ---- h1 = Y_root + b + sum_r mean(Y_rel[src]) (gather-mean, no atomics) ----
  agg_h1_k<<<dim3((N_NODES + 3) / 4), blk, 0, stream>>>(Y, b_rgcn, off, esrc, h1h);

  // ---- QKVS (fp16, N=2048 = [q|k|v|skip]) = h1 @ Wt_qk + bias_cat ----
  gemm_mfma_k<1><<<dim3(2048 / 128, (N_NODES + 127) / 128), blk, 0, stream>>>(
      h1h, Wt_qk, bias_cat, QKVS, N_NODES, 2048, 256);

  // ---- fused attention: outh = attn(q,k,v) + skip (fp16) ----
  attn_fused_k<<<dim3((N_NODES + 3) / 4), blk, 0, stream>>>(QKVS, off, esrc, outh);

  // ---- BatchNorm + LeakyReLU: fp16 in, fp32 out to d_out ----
  bn_stats_k<<<dim3(208), blk, 0, stream>>>(outh, bnsum, bnsq);
  bn_apply_k<<<dim3((N_NODES * C2DIM / 8 + 255) / 256), blk, 0, stream>>>(
      outh, out, bnsum, bnsq, gamma, beta, N_NODES * C2DIM / 8);
}

// Round 10
// 358.430 us; speedup vs baseline: 1.0316x; 1.0316x over previous
//
#include <hip/hip_runtime.h>

// ---------------- problem constants ----------------
static const int N_NODES = 20000;
static const int N_EDGES = 320000;
static const int GDIM    = 256;   // input feature dim
static const int H1DIM   = 256;   // RGCN output dim
static const int C2DIM   = 512;   // HEADS * H2
static const int NREL    = 8;
static const int NSEG    = N_NODES * NREL;   // 160000

typedef _Float16 __attribute__((ext_vector_type(8))) half8;
typedef _Float16 __attribute__((ext_vector_type(4))) half4;
typedef _Float16 __attribute__((ext_vector_type(2))) half2v;
typedef __attribute__((ext_vector_type(4))) float f32x4;

__device__ __forceinline__ void gload_lds16(const void* g, void* l) {
  __builtin_amdgcn_global_load_lds(
      (const __attribute__((address_space(1))) unsigned int*)g,
      (__attribute__((address_space(3))) unsigned int*)l, 16, 0, 0);
}

// bijective XCD-chunked block swizzle (m204)
__device__ __forceinline__ void swz_bxy(int& bx, int& by) {
  int nx   = gridDim.x;
  int nwg  = nx * gridDim.y;
  int orig = blockIdx.y * nx + blockIdx.x;
  int xcd  = orig & 7;
  int q    = nwg >> 3, r = nwg & 7;
  int base = xcd < r ? xcd * (q + 1) : r * (q + 1) + (xcd - r) * q;
  int wgid = base + (orig >> 3);
  bx = wgid % nx; by = wgid / nx;
}

// ---------------- fp16 MFMA GEMM: C = A(MxK) @ Bt(NxK)^T + bias ----------------
// 128x128 tile, 4 waves (2x2), BK=64. global_load_lds dwordx4 staging with
// linear LDS dest + pre-swizzled global source (rule-21 involution c ^= row&7).
template<int OUT_HALF>
__global__ __launch_bounds__(256) void gemm_mfma_k(
    const _Float16* __restrict__ A, const _Float16* __restrict__ Bt,
    const float* __restrict__ bias, void* __restrict__ Cout,
    int M, int N, int K)
{
  __shared__ _Float16 As[128 * 64];
  __shared__ _Float16 Bs[128 * 64];
  int bx, by; swz_bxy(bx, by);
  const int tid  = threadIdx.x;
  const int wid  = tid >> 6, lane = tid & 63;
  const int wr   = wid >> 1, wc = wid & 1;
  const int brow = by * 128;
  const int bcol = bx * 128;
  const int l15  = lane & 15, lhi = lane >> 4;
  const int srow = wid * 32;
  const int lrow = lane >> 3;
  const int lchk = lane & 7;

  f32x4 acc[4][4] = {};

  for (int k0 = 0; k0 < K; k0 += 64) {
    __syncthreads();
#pragma unroll
    for (int i = 0; i < 4; ++i) {
      int row = srow + i * 8 + lrow;
      int gc  = lchk ^ (row & 7);
      gload_lds16(A  + (size_t)(brow + row) * K + k0 + gc * 8,
                  &As[(srow + i * 8) * 64]);
      gload_lds16(Bt + (size_t)(bcol + row) * K + k0 + gc * 8,
                  &Bs[(srow + i * 8) * 64]);
    }
    __syncthreads();
#pragma unroll
    for (int kf = 0; kf < 2; ++kf) {
      int cc = kf * 4 + lhi;
      half8 af[4], bfr[4];
#pragma unroll
      for (int mi = 0; mi < 4; ++mi) {
        int row = wr * 64 + mi * 16 + l15;
        af[mi] = ((const half8*)As)[row * 8 + (cc ^ (row & 7))];
      }
#pragma unroll
      for (int ni = 0; ni < 4; ++ni) {
        int row = wc * 64 + ni * 16 + l15;
        bfr[ni] = ((const half8*)Bs)[row * 8 + (cc ^ (row & 7))];
      }
#pragma unroll
      for (int mi = 0; mi < 4; ++mi)
#pragma unroll
        for (int ni = 0; ni < 4; ++ni)
          acc[mi][ni] = __builtin_amdgcn_mfma_f32_16x16x32_f16(
              af[mi], bfr[ni], acc[mi][ni], 0, 0, 0);
    }
  }
#pragma unroll
  for (int ni = 0; ni < 4; ++ni) {
    int col = bcol + wc * 64 + ni * 16 + l15;
    float bb = bias ? bias[col] : 0.f;
#pragma unroll
    for (int mi = 0; mi < 4; ++mi) {
      int row0 = brow + wr * 64 + mi * 16 + lhi * 4;
#pragma unroll
      for (int j = 0; j < 4; ++j) {
        int r = row0 + j;
        if (r >= M) continue;
        float val = acc[mi][ni][j] + bb;
        if (OUT_HALF) ((_Float16*)Cout)[(size_t)r * N + col] = (_Float16)val;
        else          ((float*)Cout)[(size_t)r * N + col] = val;
      }
    }
  }
}

// ---------------- fused prep: hist + W conversions + x->fp16 ----------------
// blocks [0,1250): hist; [1250,3554): Wt_cat (256 rows n, 2304 cols k);
// [3554,5602): Wt_qk+bias; [5602,10602): xh
__global__ __launch_bounds__(256) void prep_k(
    const int* __restrict__ dst, const int* __restrict__ et, int* __restrict__ hist,
    const float* __restrict__ W_root, const float* __restrict__ W_rel,
    _Float16* __restrict__ Wt_cat,
    const float* __restrict__ Wq, const float* __restrict__ Wk,
    const float* __restrict__ Wv, const float* __restrict__ Ws,
    const float* __restrict__ bq, const float* __restrict__ bk,
    const float* __restrict__ bv, const float* __restrict__ bs,
    _Float16* __restrict__ Wt_qk, float* __restrict__ bias_cat,
    const float* __restrict__ x, _Float16* __restrict__ xh)
{
  int b = blockIdx.x, tid = threadIdx.x;
  if (b < 1250) {                               // edge histogram
    int e = b * 256 + tid;
    if (e < N_EDGES) atomicAdd(&hist[dst[e] * NREL + et[e]], 1);
  } else if (b < 3554) {                        // Wt_cat: 256 x 2304 (n-major)
    int idx = (b - 1250) * 256 + tid;           // < 589,824
    int n = idx / 2304, k = idx % 2304;
    float v = (k < 256) ? W_root[(size_t)k * H1DIM + n]
                        : W_rel[(size_t)(k - 256) * H1DIM + n];
    Wt_cat[idx] = (_Float16)v;
  } else if (b < 5602) {                        // Wt_qk: 2048 x 256 (+ bias)
    int idx = (b - 3554) * 256 + tid;           // < 524,288
    int n = idx >> 8, k = idx & 255;
    int sel = n >> 9, c = n & 511;
    const float* W = sel == 0 ? Wq : sel == 1 ? Wk : sel == 2 ? Wv : Ws;
    Wt_qk[(size_t)n * 256 + k] = (_Float16)W[(size_t)k * C2DIM + c];
    if (k == 0) {
      const float* B = sel == 0 ? bq : sel == 1 ? bk : sel == 2 ? bv : bs;
      bias_cat[n] = B[c];
    }
  } else {                                      // x -> fp16, float4 granularity
    int i = (b - 5602) * 256 + tid;             // < 1,280,000
    float4 v = ((const float4*)x)[i];
    half4 o = {(_Float16)v.x, (_Float16)v.y, (_Float16)v.z, (_Float16)v.w};
    ((half4*)xh)[i] = o;
  }
}

// ---------------- scan: local pass ----------------
__global__ __launch_bounds__(1024) void scan_local_k(
    const int* __restrict__ in, int* __restrict__ out, int* __restrict__ bsum, int n)
{
  __shared__ int s[1024];
  int gi = blockIdx.x * 1024 + threadIdx.x;
  int v = gi < n ? in[gi] : 0;
  s[threadIdx.x] = v; __syncthreads();
  for (int off = 1; off < 1024; off <<= 1) {
    int t = threadIdx.x >= off ? s[threadIdx.x - off] : 0;
    __syncthreads();
    s[threadIdx.x] += t;
    __syncthreads();
  }
  if (gi < n) out[gi] = s[threadIdx.x] - v;
  if (threadIdx.x == 1023) bsum[blockIdx.x] = s[1023];
}

// addoff: each block re-scans bsum itself (nb<=1024), then offsets + cursor init
__global__ __launch_bounds__(1024) void scan_addoff_k(
    int* __restrict__ off, const int* __restrict__ bsum,
    int* __restrict__ cur, int n, int nb)
{
  __shared__ int s[1024];
  int t = threadIdx.x;
  int v = t < nb ? bsum[t] : 0;
  s[t] = v; __syncthreads();
  for (int o = 1; o < 1024; o <<= 1) {
    int u = t >= o ? s[t - o] : 0;
    __syncthreads();
    s[t] += u;
    __syncthreads();
  }
  int blockOff = blockIdx.x == 0 ? 0 : s[blockIdx.x - 1];
  int gi = blockIdx.x * 1024 + t;
  if (gi < n) {
    int val = off[gi] + blockOff;
    off[gi] = val;
    cur[gi] = val;
  }
  if (gi == 0) off[n] = N_EDGES;
}

__global__ void reorder_k(const int* __restrict__ src, const int* __restrict__ dst,
                          const int* __restrict__ et,
                          int* __restrict__ cur, int* __restrict__ esrc)
{
  int e = blockIdx.x * blockDim.x + threadIdx.x;
  if (e >= N_EDGES) return;
  int seg = dst[e] * NREL + et[e];
  esrc[atomicAdd(&cur[seg], 1)] = src[e];
}

// ---------------- build Xcat = [x | mean_r(x)] in fp16 (gathers 10MB xh) ----------------
__global__ __launch_bounds__(256) void agg_xcat_k(
    const _Float16* __restrict__ xh, const int* __restrict__ off,
    const int* __restrict__ esrc, _Float16* __restrict__ Xcat)
{
  int d = blockIdx.x * 4 + (threadIdx.x >> 6);
  if (d >= N_NODES) return;
  int lane = threadIdx.x & 63;
  _Float16* xrow = Xcat + (size_t)d * 2304;
  half4 xv = ((const half4*)(xh + (size_t)d * GDIM))[lane];
  *(half4*)(xrow + lane * 4) = xv;
  for (int r = 0; r < NREL; ++r) {
    int seg = d * NREL + r;
    int beg = off[seg], end = off[seg + 1];
    float4 acc = make_float4(0.f, 0.f, 0.f, 0.f);
    for (int e = beg; e < end; ++e) {
      int s = esrc[e];
      half4 v = ((const half4*)(xh + (size_t)s * GDIM))[lane];
      acc.x += (float)v.x; acc.y += (float)v.y;
      acc.z += (float)v.z; acc.w += (float)v.w;
    }
    float inv = (end > beg) ? 1.0f / (float)(end - beg) : 0.0f;
    half4 o;
    o.x = (_Float16)(acc.x * inv); o.y = (_Float16)(acc.y * inv);
    o.z = (_Float16)(acc.z * inv); o.w = (_Float16)(acc.w * inv);
    *(half4*)(xrow + 256 + r * 256 + lane * 4) = o;
  }
}

// ---------------- fused attention: QKVS row = [q|k|v|skip] fp16; writes fp16 outh ----------------
__global__ __launch_bounds__(256) void attn_fused_k(
    const _Float16* __restrict__ qkvs,
    const int* __restrict__ off, const int* __restrict__ esrc,
    _Float16* __restrict__ outh)
{
  int d = blockIdx.x * 4 + (threadIdx.x >> 6);
  if (d >= N_NODES) return;
  int lane = threadIdx.x & 63;
  half8 qr = ((const half8*)(qkvs + (size_t)d * 2048))[lane];
  float qf[8];
#pragma unroll
  for (int j = 0; j < 8; ++j) qf[j] = (float)qr[j];
  float m = -3.4e38f, ssum = 0.f;
  float av[8] = {};
  int beg = off[d * NREL], end = off[d * NREL + NREL];
  half8 krN = {}, vrN = {};
  if (beg < end) {
    int s0 = esrc[beg];
    const half8* row = (const half8*)(qkvs + (size_t)s0 * 2048 + 512);
    krN = row[lane];
    vrN = row[64 + lane];
  }
  for (int e = beg; e < end; ++e) {
    half8 kr = krN, vr = vrN;
    if (e + 1 < end) {
      int s1 = esrc[e + 1];
      const half8* row = (const half8*)(qkvs + (size_t)s1 * 2048 + 512);
      krN = row[lane];
      vrN = row[64 + lane];
    }
    float p = 0.f;
#pragma unroll
    for (int j = 0; j < 8; ++j) p += qf[j] * (float)kr[j];
    p += __shfl_xor(p, 1); p += __shfl_xor(p, 2);
    p += __shfl_xor(p, 4); p += __shfl_xor(p, 8);
    float a = p * 0.08838834764831845f;      // 1/sqrt(128)
    float mn = fmaxf(m, a);
    float corr = __expf(m - mn), w = __expf(a - mn);
    ssum = ssum * corr + w;
#pragma unroll
    for (int j = 0; j < 8; ++j) av[j] = av[j] * corr + w * (float)vr[j];
    m = mn;
  }
  float inv = 1.0f / fmaxf(ssum, 1e-16f);
  half8 sr = ((const half8*)(qkvs + (size_t)d * 2048 + 1536))[lane];  // skip
  half8 o;
#pragma unroll
  for (int j = 0; j < 8; ++j) o[j] = (_Float16)(av[j] * inv + (float)sr[j]);
  ((half8*)(outh + (size_t)d * C2DIM))[lane] = o;
}

// ---------------- BN on fp16 input ----------------
__global__ __launch_bounds__(256) void bn_stats_k(
    const _Float16* __restrict__ x, float* __restrict__ sums, float* __restrict__ sumsq)
{
  int t = threadIdx.x;            // cols 2t, 2t+1
  float s0 = 0.f, q0 = 0.f, s1 = 0.f, q1 = 0.f;
  for (int row = blockIdx.x; row < N_NODES; row += gridDim.x) {
    half2v v = ((const half2v*)(x + (size_t)row * C2DIM))[t];
    float a = (float)v.x, b = (float)v.y;
    s0 += a; q0 += a * a; s1 += b; q1 += b * b;
  }
  atomicAdd(&sums[2 * t], s0);  atomicAdd(&sums[2 * t + 1], s1);
  atomicAdd(&sumsq[2 * t], q0); atomicAdd(&sumsq[2 * t + 1], q1);
}

// apply: fp16 in, fp32 out, inline scale/shift (statically-indexed)
__global__ void bn_apply_k(const _Float16* __restrict__ xin, float* __restrict__ xout,
                           const float* __restrict__ sums, const float* __restrict__ sumsq,
                           const float* __restrict__ gamma, const float* __restrict__ beta,
                           int total8)
{
  int i = blockIdx.x * blockDim.x + threadIdx.x;
  if (i >= total8) return;
  int c0 = (i & 63) * 8;
  half8 v = ((const half8*)xin)[i];
  float o[8];
#pragma unroll
  for (int j = 0; j < 8; ++j) {
    int c = c0 + j;
    float mu  = sums[c] * (1.0f / N_NODES);
    float var = sumsq[c] * (1.0f / N_NODES) - mu * mu;
    float sc  = gamma[c] * rsqrtf(var + 1e-5f);
    float val = ((float)v[j] - mu) * sc + beta[c];
    o[j] = val >= 0.f ? val : 0.01f * val;
  }
  ((float4*)xout)[i * 2]     = make_float4(o[0], o[1], o[2], o[3]);
  ((float4*)xout)[i * 2 + 1] = make_float4(o[4], o[5], o[6], o[7]);
}

// ---------------- launch ----------------
extern "C" void kernel_launch(void* const* d_in, const int* in_sizes, int n_in,
                              void* d_out, int out_size, void* d_ws, size_t ws_size,
                              hipStream_t stream)
{
  const float* x      = (const float*)d_in[0];
  const int*   ei     = (const int*)d_in[2];
  const int*   src    = ei;
  const int*   dst    = ei + N_EDGES;
  const int*   etype  = (const int*)d_in[3];
  const float* W_rel  = (const float*)d_in[4];
  const float* W_root = (const float*)d_in[5];
  const float* b_rgcn = (const float*)d_in[6];
  const float* W_q = (const float*)d_in[7];  const float* b_q = (const float*)d_in[8];
  const float* W_k = (const float*)d_in[9];  const float* b_k = (const float*)d_in[10];
  const float* W_v = (const float*)d_in[11]; const float* b_v = (const float*)d_in[12];
  const float* W_s = (const float*)d_in[13]; const float* b_s = (const float*)d_in[14];
  const float* gamma = (const float*)d_in[15];
  const float* beta  = (const float*)d_in[16];
  float* out = (float*)d_out;

  // ---- workspace layout ----
  char* ws = (char*)d_ws;
  _Float16* Xcat   = (_Float16*)(ws + 0);          // N x 2304 fp16 = 92,160,000
  _Float16* QKVS   = (_Float16*)(ws + 0);          // reuse after h1 GEMM: N x 2048 = 81,920,000
  _Float16* outh   = (_Float16*)(ws + 81920000);   // N x 512 fp16 (clobbers dead Wt/h1h tail)
  _Float16* Wt_cat = (_Float16*)(ws + 92160000);   // 256 x 2304 fp16 = 1,179,648
  _Float16* Wt_qk  = (_Float16*)(ws + 93339648);   // 2048 x 256 fp16 = 1,048,576
  _Float16* h1h    = (_Float16*)(ws + 94388224);   // N x 256 fp16 = 10,240,000
  _Float16* xh     = h1h;                          // xh aliases h1h (dead before h1 GEMM writes)

  char* C = ws + 104628224;                    // CSR + small area
  int*   cur      = (int*)(C + 0);             // 640,000  (hist, then cursor)
  float* bns      = (float*)(C + 640000);      // 8,192
  float* bias_cat = (float*)(C + 648192);      // 8,192
  int*   off      = (int*)(C + 656384);        // 640,016
  int*   esrc     = (int*)(C + 1296400);       // 1,280,000
  int*   bsum     = (int*)(C + 2576400);       // 4,096  (ends 107,208,720)
  float* bnsum = bns, *bnsq = bns + 512;

  hipMemsetAsync(C, 0, 648192, stream);        // hist + bns in one call

  dim3 blk(256);
  const int NB = (NSEG + 1023) / 1024;         // 157

  // ---- fused prep: hist + weight conversions + x->fp16 ----
  prep_k<<<dim3(10602), blk, 0, stream>>>(
      dst, etype, cur,
      W_root, W_rel, Wt_cat,
      W_q, W_k, W_v, W_s, b_q, b_k, b_v, b_s, Wt_qk, bias_cat,
      x, xh);

  // ---- CSR scan + reorder ----
  scan_local_k<<<dim3(NB), dim3(1024), 0, stream>>>(cur, off, bsum, NSEG);
  scan_addoff_k<<<dim3(NB), dim3(1024), 0, stream>>>(off, bsum, cur, NSEG, NB);
  reorder_k<<<dim3((N_EDGES + 255) / 256), blk, 0, stream>>>(
      src, dst, etype, cur, esrc);

  // ---- Xcat = [x | mean_r(x)] (gathers from 10MB xh, L2/L3-resident) ----
  agg_xcat_k<<<dim3((N_NODES + 3) / 4), blk, 0, stream>>>(xh, off, esrc, Xcat);

  // ---- h1 (fp16) = Xcat @ Wt_cat + b_rgcn : K=2304 GEMM (overwrites xh) ----
  gemm_mfma_k<1><<<dim3(H1DIM / 128, (N_NODES + 127) / 128), blk, 0, stream>>>(
      Xcat, Wt_cat, b_rgcn, h1h, N_NODES, H1DIM, 2304);

  // ---- QKVS (fp16, N=2048 = [q|k|v|skip]) = h1 @ Wt_qk + bias_cat ----
  gemm_mfma_k<1><<<dim3(2048 / 128, (N_NODES + 127) / 128), blk, 0, stream>>>(
      h1h, Wt_qk, bias_cat, QKVS, N_NODES, 2048, 256);

  // ---- fused attention: outh = attn(q,k,v) + skip (fp16) ----
  attn_fused_k<<<dim3((N_NODES + 3) / 4), blk, 0, stream>>>(QKVS, off, esrc, outh);

  // ---- BatchNorm + LeakyReLU: fp16 in, fp32 out to d_out ----
  bn_stats_k<<<dim3(208), blk, 0, stream>>>(outh, bnsum, bnsq);
  bn_apply_k<<<dim3((N_NODES * C2DIM / 8 + 255) / 256), blk, 0, stream>>>(
      outh, out, bnsum, bnsq, gamma, beta, N_NODES * C2DIM / 8);
}

// Round 11
// 343.067 us; speedup vs baseline: 1.0778x; 1.0448x over previous
//
#include <hip/hip_runtime.h>

// ---------------- problem constants ----------------
static const int N_NODES = 20000;
static const int N_EDGES = 320000;
static const int GDIM    = 256;   // input feature dim
static const int H1DIM   = 256;   // RGCN output dim
static const int C2DIM   = 512;   // HEADS * H2
static const int NREL    = 8;
static const int NSEG    = N_NODES * NREL;   // 160000

typedef _Float16 __attribute__((ext_vector_type(8))) half8;
typedef _Float16 __attribute__((ext_vector_type(4))) half4;
typedef _Float16 __attribute__((ext_vector_type(2))) half2v;
typedef __attribute__((ext_vector_type(4))) float f32x4;

__device__ __forceinline__ void gload_lds16(const void* g, void* l) {
  __builtin_amdgcn_global_load_lds(
      (const __attribute__((address_space(1))) unsigned int*)g,
      (__attribute__((address_space(3))) unsigned int*)l, 16, 0, 0);
}

// bijective XCD-chunked block swizzle (m204)
__device__ __forceinline__ void swz_bxy(int& bx, int& by) {
  int nx   = gridDim.x;
  int nwg  = nx * gridDim.y;
  int orig = blockIdx.y * nx + blockIdx.x;
  int xcd  = orig & 7;
  int q    = nwg >> 3, r = nwg & 7;
  int base = xcd < r ? xcd * (q + 1) : r * (q + 1) + (xcd - r) * q;
  int wgid = base + (orig >> 3);
  bx = wgid % nx; by = wgid / nx;
}

// ---------------- fp16 MFMA GEMM: 128x128 tile (used for QKVS, N=2048) ----------------
template<int OUT_HALF>
__global__ __launch_bounds__(256) void gemm_mfma_k(
    const _Float16* __restrict__ A, const _Float16* __restrict__ Bt,
    const float* __restrict__ bias, void* __restrict__ Cout,
    int M, int N, int K)
{
  __shared__ _Float16 As[128 * 64];
  __shared__ _Float16 Bs[128 * 64];
  int bx, by; swz_bxy(bx, by);
  const int tid  = threadIdx.x;
  const int wid  = tid >> 6, lane = tid & 63;
  const int wr   = wid >> 1, wc = wid & 1;
  const int brow = by * 128;
  const int bcol = bx * 128;
  const int l15  = lane & 15, lhi = lane >> 4;
  const int srow = wid * 32;
  const int lrow = lane >> 3;
  const int lchk = lane & 7;

  f32x4 acc[4][4] = {};

  for (int k0 = 0; k0 < K; k0 += 64) {
    __syncthreads();
#pragma unroll
    for (int i = 0; i < 4; ++i) {
      int row = srow + i * 8 + lrow;
      int gc  = lchk ^ (row & 7);
      gload_lds16(A  + (size_t)(brow + row) * K + k0 + gc * 8,
                  &As[(srow + i * 8) * 64]);
      gload_lds16(Bt + (size_t)(bcol + row) * K + k0 + gc * 8,
                  &Bs[(srow + i * 8) * 64]);
    }
    __syncthreads();
#pragma unroll
    for (int kf = 0; kf < 2; ++kf) {
      int cc = kf * 4 + lhi;
      half8 af[4], bfr[4];
#pragma unroll
      for (int mi = 0; mi < 4; ++mi) {
        int row = wr * 64 + mi * 16 + l15;
        af[mi] = ((const half8*)As)[row * 8 + (cc ^ (row & 7))];
      }
#pragma unroll
      for (int ni = 0; ni < 4; ++ni) {
        int row = wc * 64 + ni * 16 + l15;
        bfr[ni] = ((const half8*)Bs)[row * 8 + (cc ^ (row & 7))];
      }
#pragma unroll
      for (int mi = 0; mi < 4; ++mi)
#pragma unroll
        for (int ni = 0; ni < 4; ++ni)
          acc[mi][ni] = __builtin_amdgcn_mfma_f32_16x16x32_f16(
              af[mi], bfr[ni], acc[mi][ni], 0, 0, 0);
    }
  }
#pragma unroll
  for (int ni = 0; ni < 4; ++ni) {
    int col = bcol + wc * 64 + ni * 16 + l15;
    float bb = bias ? bias[col] : 0.f;
#pragma unroll
    for (int mi = 0; mi < 4; ++mi) {
      int row0 = brow + wr * 64 + mi * 16 + lhi * 4;
#pragma unroll
      for (int j = 0; j < 4; ++j) {
        int r = row0 + j;
        if (r >= M) continue;
        float val = acc[mi][ni][j] + bb;
        if (OUT_HALF) ((_Float16*)Cout)[(size_t)r * N + col] = (_Float16)val;
        else          ((float*)Cout)[(size_t)r * N + col] = val;
      }
    }
  }
}

// ---------------- fp16 MFMA GEMM: 64x64 tile, split-A (h1: narrow-N, deep-K) ----------------
// 4 waves (2x2), each wave 32x32 out. 4x the block count of the 128-tile at N=256
// -> ~5 blocks/CU (occupancy fix). A is read from A1 (k < ksplit) / A2 (k >= ksplit).
__global__ __launch_bounds__(256) void gemm64_split_k(
    const _Float16* __restrict__ A1, int lda1,
    const _Float16* __restrict__ A2, int lda2, int ksplit,
    const _Float16* __restrict__ Bt, const float* __restrict__ bias,
    _Float16* __restrict__ Cout, int M, int N, int K)
{
  __shared__ _Float16 As[64 * 64];
  __shared__ _Float16 Bs[64 * 64];
  int bx, by; swz_bxy(bx, by);
  const int tid  = threadIdx.x;
  const int wid  = tid >> 6, lane = tid & 63;
  const int wr   = wid >> 1, wc = wid & 1;
  const int brow = by * 64;
  const int bcol = bx * 64;
  const int l15  = lane & 15, lhi = lane >> 4;
  const int lrow = lane >> 3;
  const int lchk = lane & 7;

  f32x4 acc[2][2] = {};

  for (int k0 = 0; k0 < K; k0 += 64) {
    const _Float16* Ab; int lda, ac;
    if (k0 < ksplit) { Ab = A1; lda = lda1; ac = k0; }
    else             { Ab = A2; lda = lda2; ac = k0 - ksplit; }
    __syncthreads();
#pragma unroll
    for (int i = 0; i < 2; ++i) {
      int row = wid * 16 + i * 8 + lrow;      // 0..63, each row once
      int gc  = lchk ^ (row & 7);             // rule-21 pre-swizzled source
      gload_lds16(Ab + (size_t)(brow + row) * lda + ac + gc * 8,
                  &As[(wid * 16 + i * 8) * 64]);
      gload_lds16(Bt + (size_t)(bcol + row) * K + k0 + gc * 8,
                  &Bs[(wid * 16 + i * 8) * 64]);
    }
    __syncthreads();
#pragma unroll
    for (int kf = 0; kf < 2; ++kf) {
      int cc = kf * 4 + lhi;
      half8 af[2], bfr[2];
#pragma unroll
      for (int mi = 0; mi < 2; ++mi) {
        int row = wr * 32 + mi * 16 + l15;
        af[mi] = ((const half8*)As)[row * 8 + (cc ^ (row & 7))];
      }
#pragma unroll
      for (int ni = 0; ni < 2; ++ni) {
        int row = wc * 32 + ni * 16 + l15;
        bfr[ni] = ((const half8*)Bs)[row * 8 + (cc ^ (row & 7))];
      }
#pragma unroll
      for (int mi = 0; mi < 2; ++mi)
#pragma unroll
        for (int ni = 0; ni < 2; ++ni)
          acc[mi][ni] = __builtin_amdgcn_mfma_f32_16x16x32_f16(
              af[mi], bfr[ni], acc[mi][ni], 0, 0, 0);
    }
  }
#pragma unroll
  for (int ni = 0; ni < 2; ++ni) {
    int col = bcol + wc * 32 + ni * 16 + l15;
    float bb = bias ? bias[col] : 0.f;
#pragma unroll
    for (int mi = 0; mi < 2; ++mi) {
      int row0 = brow + wr * 32 + mi * 16 + lhi * 4;
#pragma unroll
      for (int j = 0; j < 4; ++j) {
        int r = row0 + j;
        if (r >= M) continue;
        Cout[(size_t)r * N + col] = (_Float16)(acc[mi][ni][j] + bb);
      }
    }
  }
}

// ---------------- fused prep: hist + W conversions + x->fp16 ----------------
// blocks [0,1250): hist; [1250,3554): Wt_cat (256 rows n, 2304 cols k);
// [3554,5602): Wt_qk+bias; [5602,10602): xh
__global__ __launch_bounds__(256) void prep_k(
    const int* __restrict__ dst, const int* __restrict__ et, int* __restrict__ hist,
    const float* __restrict__ W_root, const float* __restrict__ W_rel,
    _Float16* __restrict__ Wt_cat,
    const float* __restrict__ Wq, const float* __restrict__ Wk,
    const float* __restrict__ Wv, const float* __restrict__ Ws,
    const float* __restrict__ bq, const float* __restrict__ bk,
    const float* __restrict__ bv, const float* __restrict__ bs,
    _Float16* __restrict__ Wt_qk, float* __restrict__ bias_cat,
    const float* __restrict__ x, _Float16* __restrict__ xh)
{
  int b = blockIdx.x, tid = threadIdx.x;
  if (b < 1250) {                               // edge histogram
    int e = b * 256 + tid;
    if (e < N_EDGES) atomicAdd(&hist[dst[e] * NREL + et[e]], 1);
  } else if (b < 3554) {                        // Wt_cat: 256 x 2304 (n-major)
    int idx = (b - 1250) * 256 + tid;           // < 589,824
    int n = idx / 2304, k = idx % 2304;
    float v = (k < 256) ? W_root[(size_t)k * H1DIM + n]
                        : W_rel[(size_t)(k - 256) * H1DIM + n];
    Wt_cat[idx] = (_Float16)v;
  } else if (b < 5602) {                        // Wt_qk: 2048 x 256 (+ bias)
    int idx = (b - 3554) * 256 + tid;           // < 524,288
    int n = idx >> 8, k = idx & 255;
    int sel = n >> 9, c = n & 511;
    const float* W = sel == 0 ? Wq : sel == 1 ? Wk : sel == 2 ? Wv : Ws;
    Wt_qk[(size_t)n * 256 + k] = (_Float16)W[(size_t)k * C2DIM + c];
    if (k == 0) {
      const float* B = sel == 0 ? bq : sel == 1 ? bk : sel == 2 ? bv : bs;
      bias_cat[n] = B[c];
    }
  } else {                                      // x -> fp16, float4 granularity
    int i = (b - 5602) * 256 + tid;             // < 1,280,000
    float4 v = ((const float4*)x)[i];
    half4 o = {(_Float16)v.x, (_Float16)v.y, (_Float16)v.z, (_Float16)v.w};
    ((half4*)xh)[i] = o;
  }
}

// ---------------- scan: local pass ----------------
__global__ __launch_bounds__(1024) void scan_local_k(
    const int* __restrict__ in, int* __restrict__ out, int* __restrict__ bsum, int n)
{
  __shared__ int s[1024];
  int gi = blockIdx.x * 1024 + threadIdx.x;
  int v = gi < n ? in[gi] : 0;
  s[threadIdx.x] = v; __syncthreads();
  for (int off = 1; off < 1024; off <<= 1) {
    int t = threadIdx.x >= off ? s[threadIdx.x - off] : 0;
    __syncthreads();
    s[threadIdx.x] += t;
    __syncthreads();
  }
  if (gi < n) out[gi] = s[threadIdx.x] - v;
  if (threadIdx.x == 1023) bsum[blockIdx.x] = s[1023];
}

// addoff: each block re-scans bsum itself (nb<=1024), then offsets + cursor init
__global__ __launch_bounds__(1024) void scan_addoff_k(
    int* __restrict__ off, const int* __restrict__ bsum,
    int* __restrict__ cur, int n, int nb)
{
  __shared__ int s[1024];
  int t = threadIdx.x;
  int v = t < nb ? bsum[t] : 0;
  s[t] = v; __syncthreads();
  for (int o = 1; o < 1024; o <<= 1) {
    int u = t >= o ? s[t - o] : 0;
    __syncthreads();
    s[t] += u;
    __syncthreads();
  }
  int blockOff = blockIdx.x == 0 ? 0 : s[blockIdx.x - 1];
  int gi = blockIdx.x * 1024 + t;
  if (gi < n) {
    int val = off[gi] + blockOff;
    off[gi] = val;
    cur[gi] = val;
  }
  if (gi == 0) off[n] = N_EDGES;
}

__global__ void reorder_k(const int* __restrict__ src, const int* __restrict__ dst,
                          const int* __restrict__ et,
                          int* __restrict__ cur, int* __restrict__ esrc)
{
  int e = blockIdx.x * blockDim.x + threadIdx.x;
  if (e >= N_EDGES) return;
  int seg = dst[e] * NREL + et[e];
  esrc[atomicAdd(&cur[seg], 1)] = src[e];
}

// ---------------- build Xme = [mean_r(x)] (N x 2048) in fp16 (gathers 10MB xh) ----------------
__global__ __launch_bounds__(256) void agg_xme_k(
    const _Float16* __restrict__ xh, const int* __restrict__ off,
    const int* __restrict__ esrc, _Float16* __restrict__ Xme)
{
  int d = blockIdx.x * 4 + (threadIdx.x >> 6);
  if (d >= N_NODES) return;
  int lane = threadIdx.x & 63;
  _Float16* mrow = Xme + (size_t)d * 2048;
  for (int r = 0; r < NREL; ++r) {
    int seg = d * NREL + r;
    int beg = off[seg], end = off[seg + 1];
    float4 acc = make_float4(0.f, 0.f, 0.f, 0.f);
    for (int e = beg; e < end; ++e) {
      int s = esrc[e];
      half4 v = ((const half4*)(xh + (size_t)s * GDIM))[lane];
      acc.x += (float)v.x; acc.y += (float)v.y;
      acc.z += (float)v.z; acc.w += (float)v.w;
    }
    float inv = (end > beg) ? 1.0f / (float)(end - beg) : 0.0f;
    half4 o;
    o.x = (_Float16)(acc.x * inv); o.y = (_Float16)(acc.y * inv);
    o.z = (_Float16)(acc.z * inv); o.w = (_Float16)(acc.w * inv);
    *(half4*)(mrow + r * 256 + lane * 4) = o;
  }
}

// ---------------- fused attention: QKVS row = [q|k|v|skip] fp16; writes fp16 outh ----------------
__global__ __launch_bounds__(256) void attn_fused_k(
    const _Float16* __restrict__ qkvs,
    const int* __restrict__ off, const int* __restrict__ esrc,
    _Float16* __restrict__ outh)
{
  int d = blockIdx.x * 4 + (threadIdx.x >> 6);
  if (d >= N_NODES) return;
  int lane = threadIdx.x & 63;
  half8 qr = ((const half8*)(qkvs + (size_t)d * 2048))[lane];
  float qf[8];
#pragma unroll
  for (int j = 0; j < 8; ++j) qf[j] = (float)qr[j];
  float m = -3.4e38f, ssum = 0.f;
  float av[8] = {};
  int beg = off[d * NREL], end = off[d * NREL + NREL];
  half8 krN = {}, vrN = {};
  if (beg < end) {
    int s0 = esrc[beg];
    const half8* row = (const half8*)(qkvs + (size_t)s0 * 2048 + 512);
    krN = row[lane];
    vrN = row[64 + lane];
  }
  for (int e = beg; e < end; ++e) {
    half8 kr = krN, vr = vrN;
    if (e + 1 < end) {
      int s1 = esrc[e + 1];
      const half8* row = (const half8*)(qkvs + (size_t)s1 * 2048 + 512);
      krN = row[lane];
      vrN = row[64 + lane];
    }
    float p = 0.f;
#pragma unroll
    for (int j = 0; j < 8; ++j) p += qf[j] * (float)kr[j];
    p += __shfl_xor(p, 1); p += __shfl_xor(p, 2);
    p += __shfl_xor(p, 4); p += __shfl_xor(p, 8);
    float a = p * 0.08838834764831845f;      // 1/sqrt(128)
    float mn = fmaxf(m, a);
    float corr = __expf(m - mn), w = __expf(a - mn);
    ssum = ssum * corr + w;
#pragma unroll
    for (int j = 0; j < 8; ++j) av[j] = av[j] * corr + w * (float)vr[j];
    m = mn;
  }
  float inv = 1.0f / fmaxf(ssum, 1e-16f);
  half8 sr = ((const half8*)(qkvs + (size_t)d * 2048 + 1536))[lane];  // skip
  half8 o;
#pragma unroll
  for (int j = 0; j < 8; ++j) o[j] = (_Float16)(av[j] * inv + (float)sr[j]);
  ((half8*)(outh + (size_t)d * C2DIM))[lane] = o;
}

// ---------------- BN on fp16 input ----------------
__global__ __launch_bounds__(256) void bn_stats_k(
    const _Float16* __restrict__ x, float* __restrict__ sums, float* __restrict__ sumsq)
{
  int t = threadIdx.x;            // cols 2t, 2t+1
  float s0 = 0.f, q0 = 0.f, s1 = 0.f, q1 = 0.f;
  for (int row = blockIdx.x; row < N_NODES; row += gridDim.x) {
    half2v v = ((const half2v*)(x + (size_t)row * C2DIM))[t];
    float a = (float)v.x, b = (float)v.y;
    s0 += a; q0 += a * a; s1 += b; q1 += b * b;
  }
  atomicAdd(&sums[2 * t], s0);  atomicAdd(&sums[2 * t + 1], s1);
  atomicAdd(&sumsq[2 * t], q0); atomicAdd(&sumsq[2 * t + 1], q1);
}

// apply: fp16 in, fp32 out, inline scale/shift (statically-indexed)
__global__ void bn_apply_k(const _Float16* __restrict__ xin, float* __restrict__ xout,
                           const float* __restrict__ sums, const float* __restrict__ sumsq,
                           const float* __restrict__ gamma, const float* __restrict__ beta,
                           int total8)
{
  int i = blockIdx.x * blockDim.x + threadIdx.x;
  if (i >= total8) return;
  int c0 = (i & 63) * 8;
  half8 v = ((const half8*)xin)[i];
  float o[8];
#pragma unroll
  for (int j = 0; j < 8; ++j) {
    int c = c0 + j;
    float mu  = sums[c] * (1.0f / N_NODES);
    float var = sumsq[c] * (1.0f / N_NODES) - mu * mu;
    float sc  = gamma[c] * rsqrtf(var + 1e-5f);
    float val = ((float)v[j] - mu) * sc + beta[c];
    o[j] = val >= 0.f ? val : 0.01f * val;
  }
  ((float4*)xout)[i * 2]     = make_float4(o[0], o[1], o[2], o[3]);
  ((float4*)xout)[i * 2 + 1] = make_float4(o[4], o[5], o[6], o[7]);
}

// ---------------- launch ----------------
extern "C" void kernel_launch(void* const* d_in, const int* in_sizes, int n_in,
                              void* d_out, int out_size, void* d_ws, size_t ws_size,
                              hipStream_t stream)
{
  const float* x      = (const float*)d_in[0];
  const int*   ei     = (const int*)d_in[2];
  const int*   src    = ei;
  const int*   dst    = ei + N_EDGES;
  const int*   etype  = (const int*)d_in[3];
  const float* W_rel  = (const float*)d_in[4];
  const float* W_root = (const float*)d_in[5];
  const float* b_rgcn = (const float*)d_in[6];
  const float* W_q = (const float*)d_in[7];  const float* b_q = (const float*)d_in[8];
  const float* W_k = (const float*)d_in[9];  const float* b_k = (const float*)d_in[10];
  const float* W_v = (const float*)d_in[11]; const float* b_v = (const float*)d_in[12];
  const float* W_s = (const float*)d_in[13]; const float* b_s = (const float*)d_in[14];
  const float* gamma = (const float*)d_in[15];
  const float* beta  = (const float*)d_in[16];
  float* out = (float*)d_out;

  // ---- workspace layout ----
  char* ws = (char*)d_ws;
  _Float16* Xme    = (_Float16*)(ws + 0);          // N x 2048 fp16 = 81,920,000 (means)
  _Float16* QKVS   = (_Float16*)(ws + 0);          // reuse after h1 GEMM: N x 2048
  _Float16* outh   = (_Float16*)(ws + 81920000);   // N x 512 fp16 (clobbers dead Wt/h1h tail)
  _Float16* Wt_cat = (_Float16*)(ws + 92160000);   // 256 x 2304 fp16 = 1,179,648
  _Float16* Wt_qk  = (_Float16*)(ws + 93339648);   // 2048 x 256 fp16 = 1,048,576
  _Float16* h1h    = (_Float16*)(ws + 94388224);   // N x 256 fp16 = 10,240,000
  _Float16* xh     = h1h;                          // xh aliases h1h (dead before h1 GEMM writes)

  char* C = ws + 104628224;                    // CSR + small area
  int*   cur      = (int*)(C + 0);             // 640,000  (hist, then cursor)
  float* bns      = (float*)(C + 640000);      // 8,192
  float* bias_cat = (float*)(C + 648192);      // 8,192
  int*   off      = (int*)(C + 656384);        // 640,016
  int*   esrc     = (int*)(C + 1296400);       // 1,280,000
  int*   bsum     = (int*)(C + 2576400);       // 4,096  (ends 107,208,720)
  float* bnsum = bns, *bnsq = bns + 512;

  hipMemsetAsync(C, 0, 648192, stream);        // hist + bns in one call

  dim3 blk(256);
  const int NB = (NSEG + 1023) / 1024;         // 157

  // ---- fused prep: hist + weight conversions + x->fp16 ----
  prep_k<<<dim3(10602), blk, 0, stream>>>(
      dst, etype, cur,
      W_root, W_rel, Wt_cat,
      W_q, W_k, W_v, W_s, b_q, b_k, b_v, b_s, Wt_qk, bias_cat,
      x, xh);

  // ---- CSR scan + reorder ----
  scan_local_k<<<dim3(NB), dim3(1024), 0, stream>>>(cur, off, bsum, NSEG);
  scan_addoff_k<<<dim3(NB), dim3(1024), 0, stream>>>(off, bsum, cur, NSEG, NB);
  reorder_k<<<dim3((N_EDGES + 255) / 256), blk, 0, stream>>>(
      src, dst, etype, cur, esrc);

  // ---- Xme = per-(d,rel) means (gathers from 10MB xh, L2/L3-resident) ----
  agg_xme_k<<<dim3((N_NODES + 3) / 4), blk, 0, stream>>>(xh, off, esrc, Xme);

  // ---- h1 (fp16) = [xh | Xme] @ Wt_cat + b_rgcn : 64x64-tile split-A GEMM ----
  // grid 4 x 313 = 1252 blocks (~4.9/CU) vs 314 with the 128-tile (occupancy fix)
  gemm64_split_k<<<dim3(H1DIM / 64, (N_NODES + 63) / 64), blk, 0, stream>>>(
      xh, 256, Xme, 2048, 256, Wt_cat, b_rgcn, h1h, N_NODES, H1DIM, 2304);

  // ---- QKVS (fp16, N=2048 = [q|k|v|skip]) = h1 @ Wt_qk + bias_cat ----
  gemm_mfma_k<1><<<dim3(2048 / 128, (N_NODES + 127) / 128), blk, 0, stream>>>(
      h1h, Wt_qk, bias_cat, QKVS, N_NODES, 2048, 256);

  // ---- fused attention: outh = attn(q,k,v) + skip (fp16) ----
  attn_fused_k<<<dim3((N_NODES + 3) / 4), blk, 0, stream>>>(QKVS, off, esrc, outh);

  // ---- BatchNorm + LeakyReLU: fp16 in, fp32 out to d_out ----
  bn_stats_k<<<dim3(208), blk, 0, stream>>>(outh, bnsum, bnsq);
  bn_apply_k<<<dim3((N_NODES * C2DIM / 8 + 255) / 256), blk, 0, stream>>>(
      outh, out, bnsum, bnsq, gamma, beta, N_NODES * C2DIM / 8);
}